// Round 1
// baseline (201.197 us; speedup 1.0000x reference)
//
#include <hip/hip_runtime.h>

// Problem constants (from reference):
//   x     [B=32, I=64, K=8192]            f32
//   U_in  [I=64, R=8,  K=8192, H=4]       f32   (h innermost -> float4 per (i,r,k))
//   M     [R=8,  S=8,  K=8192, H=4]       f32
//   U_out [O=64, S=8,  K=8192, H=4]       f32
//   out   [B=32, O=64, K=8192]            f32
//
// Fully fused per (b,k):
//   r[r,h]   = sum_i U_in[i,r,k,h] * x[b,i,k]
//   s[s,h]   = sum_r M[r,s,k,h]    * r[r,h]
//   out[b,o,k] = sum_{s,h} U_out[o,s,k,h] * s[s,h]

static constexpr int IN_CH  = 64;
static constexpr int OUT_CH = 64;
static constexpr int RANK   = 8;
static constexpr int MODES  = 8192;
static constexpr int KT     = 16;   // k per block (64B segments for x/out rows)

__device__ __forceinline__ void fma_s4(float4& a, const float4 w, const float v) {
    a.x = fmaf(w.x, v, a.x);
    a.y = fmaf(w.y, v, a.y);
    a.z = fmaf(w.z, v, a.z);
    a.w = fmaf(w.w, v, a.w);
}

__device__ __forceinline__ void fma_44(float4& a, const float4 w, const float4 v) {
    a.x = fmaf(w.x, v.x, a.x);
    a.y = fmaf(w.y, v.y, a.y);
    a.z = fmaf(w.z, v.z, a.z);
    a.w = fmaf(w.w, v.w, a.w);
}

__global__ __launch_bounds__(256, 4) void diag_lr_fused(
    const float*  __restrict__ x,
    const float4* __restrict__ Uin,
    const float4* __restrict__ Mw,
    const float4* __restrict__ Uout,
    float*        __restrict__ out)
{
    const int t     = threadIdx.x;
    const int kk    = t & (KT - 1);        // 0..15  (consecutive k within wave)
    const int brow  = t >> 4;              // 0..15
    const int bid   = blockIdx.x;
    const int ktile = bid & 511;           // 0..511
    const int b     = ((bid >> 9) << 4) | brow;   // 0..31
    const int k     = ktile * KT + kk;

    // ---- stage 1: r[r][h] = sum_i U_in[i,r,k,:] * x[b,i,k] ----
    const float*  xp = x + b * (IN_CH * MODES) + k;
    const float4* up = Uin + k;

    float4 racc[RANK];
#pragma unroll
    for (int r = 0; r < RANK; ++r) racc[r] = make_float4(0.f, 0.f, 0.f, 0.f);

#pragma unroll 2
    for (int i = 0; i < IN_CH; ++i) {
        const float xv = xp[i * MODES];
        const float4* u = up + i * (RANK * MODES);
#pragma unroll
        for (int r = 0; r < RANK; ++r)
            fma_s4(racc[r], u[r * MODES], xv);
    }

    // ---- stage 2: s[s][h] = sum_r M[r,s,k,:] * r[r][h] ----
    const float4* mp = Mw + k;
    float4 sacc[RANK];
#pragma unroll
    for (int s = 0; s < RANK; ++s) {
        float4 a = make_float4(0.f, 0.f, 0.f, 0.f);
#pragma unroll
        for (int r = 0; r < RANK; ++r)
            fma_44(a, mp[(r * RANK + s) * MODES], racc[r]);
        sacc[s] = a;
    }

    // ---- stage 3: out[b,o,k] = sum_{s,h} U_out[o,s,k,h] * s[s][h] ----
    float*        op = out + b * (OUT_CH * MODES) + k;
    const float4* vp = Uout + k;

#pragma unroll 4
    for (int o = 0; o < OUT_CH; ++o) {
        float4 a = make_float4(0.f, 0.f, 0.f, 0.f);
#pragma unroll
        for (int s = 0; s < RANK; ++s)
            fma_44(a, vp[(o * RANK + s) * MODES], sacc[s]);
        op[o * MODES] = (a.x + a.y) + (a.z + a.w);
    }
}

extern "C" void kernel_launch(void* const* d_in, const int* in_sizes, int n_in,
                              void* d_out, int out_size, void* d_ws, size_t ws_size,
                              hipStream_t stream) {
    const float*  x    = (const float*)d_in[0];
    const float4* Uin  = (const float4*)d_in[1];
    const float4* Mw   = (const float4*)d_in[2];
    const float4* Uout = (const float4*)d_in[3];
    float* out = (float*)d_out;

    // 512 k-tiles (8192/16) x 2 b-halves; bid and bid+512 share k-tile -> same XCD (mod 8)
    dim3 grid(1024), block(256);
    hipLaunchKernelGGL(diag_lr_fused, grid, block, 0, stream, x, Uin, Mw, Uout, out);
}

// Round 2
// 78.954 us; speedup vs baseline: 2.5483x; 2.5483x over previous
//
#include <hip/hip_runtime.h>

// x     [B=32, I=64, K=8192]        f32
// U_in  [I=64, R=8,  K=8192, H=4]   f32  -> float4 per (i,r,k)
// M     [R=8,  S=8,  K=8192, H=4]   f32
// U_out [O=64, S=8,  K=8192, H=4]   f32
// out   [B=32, O=64, K=8192]        f32
//
// Block = 16 k x 16 b (256 thr). All weight tiles are [64 rows][16 k][4 h]
// = 16 KB chunks staged via global_load_lds, double-buffered, counted vmcnt.
// 17 phases: 8 U_in chunks, 1 M chunk, 8 U_out chunks.

static constexpr int IN_CH  = 64;
static constexpr int OUT_CH = 64;
static constexpr int RANK   = 8;
static constexpr int MODES  = 8192;
static constexpr int KT     = 16;            // k per block
static constexpr int CROWS  = 64;            // rows per chunk
static constexpr int CF4    = CROWS * KT;    // 1024 float4 = 16 KB per chunk

typedef const __attribute__((address_space(1))) void* gas_t;
typedef __attribute__((address_space(3))) void* las_t;

__device__ __forceinline__ void fma_s4(float4& a, const float4 w, const float v) {
    a.x = fmaf(w.x, v, a.x); a.y = fmaf(w.y, v, a.y);
    a.z = fmaf(w.z, v, a.z); a.w = fmaf(w.w, v, a.w);
}
__device__ __forceinline__ void fma_44(float4& a, const float4 w, const float4 v) {
    a.x = fmaf(w.x, v.x, a.x); a.y = fmaf(w.y, v.y, a.y);
    a.z = fmaf(w.z, v.z, a.z); a.w = fmaf(w.w, v.w, a.w);
}

// Stage one 16 KB chunk: 64 rows of 256 B (16 k x 4 h), row stride = MODES float4.
// Wave w loads rows [16w, 16w+16) with 4 global_load_lds_dwordx4 (1 KB each).
// LDS layout is linear [row][kk] float4 — exactly lane order (wave-uniform dest).
__device__ __forceinline__ void stage_chunk(const float4* gbase, float4* lbuf,
                                            int wid, int lane) {
    const int sub = lane >> 4;       // 0..3 : row within quad
    const int col = lane & 15;       // 0..15: k within tile
#pragma unroll
    for (int j = 0; j < 4; ++j) {
        const int row0 = wid * 16 + j * 4;                       // wave-uniform
        const float4* src = gbase + (size_t)(row0 + sub) * MODES + col;
        float4* dst = lbuf + row0 * KT;                          // wave-uniform
        __builtin_amdgcn_global_load_lds((gas_t)src, (las_t)dst, 16, 0, 0);
    }
}

__global__ __launch_bounds__(256, 4) void diag_lr_fused(
    const float*  __restrict__ x,
    const float4* __restrict__ Uin,
    const float4* __restrict__ Mw,
    const float4* __restrict__ Uout,
    float*        __restrict__ out)
{
    __shared__ float4 lds[2][CF4];   // 32 KB

    const int t    = threadIdx.x;
    const int kk   = t & 15;
    const int brow = t >> 4;
    const int lane = t & 63;
    const int wid  = t >> 6;
    const int bid  = blockIdx.x;
    const int ktile = bid & 511;
    const int b     = ((bid >> 9) << 4) | brow;
    const int k0    = ktile * KT;
    const int k     = k0 + kk;

    const float4* UinB = Uin  + k0;   // row p -> + p*MODES
    const float4* MB   = Mw   + k0;
    const float4* UoB  = Uout + k0;
    const float*  xp   = x   + (size_t)b * (IN_CH  * MODES) + k;
    float*        op   = out + (size_t)b * (OUT_CH * MODES) + k;

    // ---- prologue: stage U_in chunk 0, prefetch x chunk 0 ----
    stage_chunk(UinB, &lds[0][0], wid, lane);
    float xc[8];
#pragma unroll
    for (int ii = 0; ii < 8; ++ii) xc[ii] = xp[ii * MODES];

    float4 racc[RANK];
#pragma unroll
    for (int r = 0; r < RANK; ++r) racc[r] = make_float4(0.f, 0.f, 0.f, 0.f);

    // ---- phases 0..7: U_in chunks (chunk c lives in lds[c&1]) ----
#pragma unroll
    for (int c = 0; c < 8; ++c) {
        const int buf = c & 1;
        const float4* nxt = (c < 7) ? (UinB + (size_t)(c + 1) * CROWS * MODES) : MB;
        stage_chunk(nxt, &lds[buf ^ 1][0], wid, lane);
        asm volatile("s_waitcnt vmcnt(4)" ::: "memory"); // chunk c resident (own wave)
        __builtin_amdgcn_s_barrier();                    // all waves' rows resident
        asm volatile("" ::: "memory");                   // pin ds_reads below barrier
        float xn[8];
        if (c < 7) {
#pragma unroll
            for (int ii = 0; ii < 8; ++ii) xn[ii] = xp[((c + 1) * 8 + ii) * MODES];
        }
        const float4* Lb = &lds[buf][0];
#pragma unroll
        for (int ii = 0; ii < 8; ++ii)
#pragma unroll
            for (int r = 0; r < RANK; ++r)
                fma_s4(racc[r], Lb[(ii * 8 + r) * KT + kk], xc[ii]);
        asm volatile("" ::: "memory");                   // reads done before reuse
        __builtin_amdgcn_s_barrier();
        if (c < 7) {
#pragma unroll
            for (int ii = 0; ii < 8; ++ii) xc[ii] = xn[ii];
        }
    }

    // ---- phase 8: M (in lds[0]); stage U_out chunk 0 into lds[1] ----
    float4 sacc[RANK];
#pragma unroll
    for (int s = 0; s < RANK; ++s) sacc[s] = make_float4(0.f, 0.f, 0.f, 0.f);
    {
        stage_chunk(UoB, &lds[1][0], wid, lane);
        asm volatile("s_waitcnt vmcnt(4)" ::: "memory");
        __builtin_amdgcn_s_barrier();
        asm volatile("" ::: "memory");
        const float4* Lb = &lds[0][0];
#pragma unroll
        for (int r = 0; r < RANK; ++r)
#pragma unroll
            for (int s = 0; s < RANK; ++s)
                fma_44(sacc[s], Lb[(r * 8 + s) * KT + kk], racc[r]);
        asm volatile("" ::: "memory");
        __builtin_amdgcn_s_barrier();
    }

    // ---- phases 9..16: U_out chunks (chunk c lives in lds[(c+1)&1]) ----
#pragma unroll
    for (int c = 0; c < 8; ++c) {
        const int buf = (c + 1) & 1;
        if (c < 7) {
            stage_chunk(UoB + (size_t)(c + 1) * CROWS * MODES, &lds[buf ^ 1][0], wid, lane);
            asm volatile("s_waitcnt vmcnt(4)" ::: "memory");
        } else {
            asm volatile("s_waitcnt vmcnt(0)" ::: "memory");
        }
        __builtin_amdgcn_s_barrier();
        asm volatile("" ::: "memory");
        const float4* Lb = &lds[buf][0];
#pragma unroll
        for (int oo = 0; oo < 8; ++oo) {
            float4 a = make_float4(0.f, 0.f, 0.f, 0.f);
#pragma unroll
            for (int s = 0; s < RANK; ++s)
                fma_44(a, Lb[(oo * 8 + s) * KT + kk], sacc[s]);
            op[(c * 8 + oo) * MODES] = (a.x + a.y) + (a.z + a.w);
        }
        if (c < 7) {
            asm volatile("" ::: "memory");
            __builtin_amdgcn_s_barrier();
        }
    }
}

extern "C" void kernel_launch(void* const* d_in, const int* in_sizes, int n_in,
                              void* d_out, int out_size, void* d_ws, size_t ws_size,
                              hipStream_t stream) {
    const float*  x    = (const float*)d_in[0];
    const float4* Uin  = (const float4*)d_in[1];
    const float4* Mw   = (const float4*)d_in[2];
    const float4* Uout = (const float4*)d_in[3];
    float* out = (float*)d_out;

    dim3 grid(1024), block(256);
    hipLaunchKernelGGL(diag_lr_fused, grid, block, 0, stream, x, Uin, Mw, Uout, out);
}